// Round 8
// baseline (179.999 us; speedup 1.0000x reference)
//
#include <hip/hip_runtime.h>
#include <math.h>
#include <stdint.h>

#define BT     256            // threads per block
#define WPB    4              // waves per block
#define TOPC   64             // outputs per slice (== wave size, 1 write/lane)
#define CAPW   1024           // per-wave LDS survivor capacity
#define WT     512            // per-wave tile (64 lanes * 8 elements)
#define NSL_HI 32             // slices/row (needs 2MB workspace)
#define NSL_LO 16             // fallback slices/row (1MB workspace)
#define NC_MAX (NSL_HI * TOPC) // phase2 candidate max (2048)

// order-preserving float <-> uint mapping (monotone increasing)
__device__ __forceinline__ unsigned f2ord(float f) {
    unsigned u = __float_as_uint(f);
    return u ^ ((u & 0x80000000u) ? 0xFFFFFFFFu : 0x80000000u);
}
__device__ __forceinline__ float ord2f(unsigned k) {
    unsigned u = (k & 0x80000000u) ? (k ^ 0x80000000u) : (k ^ 0xFFFFFFFFu);
    return __uint_as_float(u);
}

// ---- wave-local exact top-64 rebuild (no barriers, no atomics; r7-verified
// structure, width-templated). Loads key/idx[0..n) (n <= G*64) into registers,
// finds the exact TOPC-th largest key vstar by 32-round bitwise ballot binary
// search, compacts (keys > vstar, then == vstar up to TOPC) to the FRONT of
// key/idx. Returns new count (= min(n, TOPC)); *out_vst = vstar.
// All lanes must call (uniform n).
template<int G>
__device__ unsigned wave_rebuild64_g(unsigned* key, int* idx, unsigned n,
                                     int lane, unsigned* out_vst)
{
    unsigned kr[G]; int ir[G];
    #pragma unroll
    for (int g = 0; g < G; ++g) {
        unsigned i = (unsigned)(g * 64 + lane);
        kr[g] = (i < n) ? key[i] : 0u;
        ir[g] = (i < n) ? idx[i] : 0;
    }
    unsigned p = 0u;
    for (int bit = 31; bit >= 0; --bit) {       // exact K-th largest (dups counted)
        unsigned t = p | (1u << bit);
        int c = 0;
        #pragma unroll
        for (int g = 0; g < G; ++g)
            c += __popcll(__ballot(kr[g] >= t)); // pads are 0, never >= t (t!=0)
        if (c >= TOPC) p = t;
    }
    const unsigned long long ltm = (1ull << lane) - 1ull;
    unsigned c = 0;
    #pragma unroll
    for (int g = 0; g < G; ++g) {               // pass 1: strictly greater (< TOPC)
        unsigned i = (unsigned)(g * 64 + lane);
        bool pa = (i < n) && (kr[g] > p);
        unsigned long long m = __ballot(pa);
        if (pa) { unsigned pos = c + (unsigned)__popcll(m & ltm); key[pos] = kr[g]; idx[pos] = ir[g]; }
        c += (unsigned)__popcll(m);
    }
    #pragma unroll
    for (int g = 0; g < G; ++g) {               // pass 2: equals fill to TOPC
        unsigned i = (unsigned)(g * 64 + lane);
        bool pa = (i < n) && (kr[g] == p);
        unsigned long long m = __ballot(pa);
        if (pa) {
            unsigned pos = c + (unsigned)__popcll(m & ltm);
            if (pos < TOPC) { key[pos] = kr[g]; idx[pos] = ir[g]; }
        }
        c += (unsigned)__popcll(m);
    }
    *out_vst = p;
    return (c < TOPC) ? c : TOPC;
}

// width dispatch (n wave-uniform)
__device__ __forceinline__ unsigned wave_rebuild64(unsigned* key, int* idx,
                                                   unsigned n, int lane,
                                                   unsigned* out_vst)
{
    if (n <= 256)  return wave_rebuild64_g<4>(key, idx, n, lane, out_vst);
    if (n <= 512)  return wave_rebuild64_g<8>(key, idx, n, lane, out_vst);
    return wave_rebuild64_g<16>(key, idx, n, lane, out_vst);
}

// Phase 1: one WAVE per slice; zero __syncthreads (r7-verified structure).
// Seed threshold via 16-bit ballot binary search over the first 1024 elements,
// stream the slice through an 8-tile fully-unrolled 4-deep register pipeline,
// append survivors via ballot-prefix positions (wave-uniform register count,
// no atomics), then wave-local exact top-64 rebuild and one coalesced 64-lane
// output write.
__global__ __launch_bounds__(BT) void phase1_topk_slices(
    const float* __restrict__ logits, uint2* __restrict__ cand,
    int V, int slice_len, int nsl)
{
    __shared__ unsigned s_key[WPB][CAPW];       // 16 KB
    __shared__ int      s_idx[WPB][CAPW];       // 16 KB

    const int row  = blockIdx.y;
    const int tid  = threadIdx.x;
    const int wid  = tid >> 6;
    const int lane = tid & 63;
    const int sl   = blockIdx.x * WPB + wid;
    const int s0   = sl * slice_len;
    int s_end = s0 + slice_len; if (s_end > V) s_end = V;   // multiple of 8 or V
    const float* rowp = logits + (size_t)row * (size_t)V;
    unsigned* mykey = s_key[wid];
    int*      myidx = s_idx[wid];
    const unsigned long long ltm = (1ull << lane) - 1ull;

    // per-tile bases / validity for tiles 0..7
    const int  tb0 = s0 + 0 * WT + lane * 8, tb1 = s0 + 1 * WT + lane * 8;
    const int  tb2 = s0 + 2 * WT + lane * 8, tb3 = s0 + 3 * WT + lane * 8;
    const int  tb4 = s0 + 4 * WT + lane * 8, tb5 = s0 + 5 * WT + lane * 8;
    const int  tb6 = s0 + 6 * WT + lane * 8, tb7 = s0 + 7 * WT + lane * 8;
    const bool vt0 = tb0 < s_end, vt1 = tb1 < s_end, vt2 = tb2 < s_end,
               vt3 = tb3 < s_end, vt4 = tb4 < s_end, vt5 = tb5 < s_end,
               vt6 = tb6 < s_end, vt7 = tb7 < s_end;

    // ---- sample tiles 0,1 ----
    float4 sa0 = {}, sb0 = {}, sa1 = {}, sb1 = {};
    if (vt0) { sa0 = *(const float4*)(rowp + tb0); sb0 = *(const float4*)(rowp + tb0 + 4); }
    if (vt1) { sa1 = *(const float4*)(rowp + tb1); sb1 = *(const float4*)(rowp + tb1 + 4); }

    // ---- issue stream tiles 2..5 into 4 slots (8 loads in flight) ----
    float4 A2 = {}, B2 = {}, A3 = {}, B3 = {};
    float4 A4 = {}, B4 = {}, A5 = {}, B5 = {};
    if (vt2) { A2 = *(const float4*)(rowp + tb2); B2 = *(const float4*)(rowp + tb2 + 4); }
    if (vt3) { A3 = *(const float4*)(rowp + tb3); B3 = *(const float4*)(rowp + tb3 + 4); }
    if (vt4) { A4 = *(const float4*)(rowp + tb4); B4 = *(const float4*)(rowp + tb4 + 4); }
    if (vt5) { A5 = *(const float4*)(rowp + tb5); B5 = *(const float4*)(rowp + tb5 + 4); }

    unsigned k0[8], k1[8];
    if (vt0) {
        k0[0] = f2ord(sa0.x); k0[1] = f2ord(sa0.y); k0[2] = f2ord(sa0.z); k0[3] = f2ord(sa0.w);
        k0[4] = f2ord(sb0.x); k0[5] = f2ord(sb0.y); k0[6] = f2ord(sb0.z); k0[7] = f2ord(sb0.w);
    } else {
        #pragma unroll
        for (int j = 0; j < 8; ++j) k0[j] = 0u;
    }
    if (vt1) {
        k1[0] = f2ord(sa1.x); k1[1] = f2ord(sa1.y); k1[2] = f2ord(sa1.z); k1[3] = f2ord(sa1.w);
        k1[4] = f2ord(sb1.x); k1[5] = f2ord(sb1.y); k1[6] = f2ord(sb1.z); k1[7] = f2ord(sb1.w);
    } else {
        #pragma unroll
        for (int j = 0; j < 8; ++j) k1[j] = 0u;
    }

    // ---- seed: 16-bit prefix ballot binary search (r5/r7-verified invariant:
    //      count(sample >= thr) >= TOPC => all slice-top-64 pass >= thr) ----
    unsigned lo = 0u, hi = 0xFFFFu;
    while (lo < hi) {                            // exactly 16 iterations
        unsigned mid = (lo + hi + 1u) >> 1;
        unsigned t = mid << 16;
        int cnt16 = 0;
        #pragma unroll
        for (int j = 0; j < 8; ++j) {
            cnt16 += __popcll(__ballot(k0[j] >= t));
            cnt16 += __popcll(__ballot(k1[j] >= t));
        }
        if (cnt16 >= TOPC) lo = mid; else hi = mid - 1u;
    }
    const unsigned thr = lo << 16;

    // ---- append: ballot-prefix positions, wave-uniform register count.
    //      MUST be called by all lanes (uniform control flow). ----
    unsigned cnt = 0u;                           // true pass count (may exceed CAPW)
    auto append8 = [&](const unsigned* k, int base, bool valid) {
        #pragma unroll
        for (int j = 0; j < 8; ++j) {
            bool pa = valid && (k[j] >= thr);
            unsigned long long m = __ballot(pa);
            if (pa) {
                unsigned pos = cnt + (unsigned)__popcll(m & ltm);
                if (pos < CAPW) { mykey[pos] = k[j]; myidx[pos] = base + j; }
            }
            cnt += (unsigned)__popcll(m);
        }
    };
    auto conv8 = [&](unsigned* k, const float4& a, const float4& b, bool valid) {
        if (valid) {
            k[0] = f2ord(a.x); k[1] = f2ord(a.y); k[2] = f2ord(a.z); k[3] = f2ord(a.w);
            k[4] = f2ord(b.x); k[5] = f2ord(b.y); k[6] = f2ord(b.z); k[7] = f2ord(b.w);
        } else {
            #pragma unroll
            for (int j = 0; j < 8; ++j) k[j] = 0u;
        }
    };

    append8(k0, tb0, vt0);
    append8(k1, tb1, vt1);

    {   // tile2 consume; refill slot with tile6
        unsigned kk[8];
        conv8(kk, A2, B2, vt2);
        if (vt6) { A2 = *(const float4*)(rowp + tb6); B2 = *(const float4*)(rowp + tb6 + 4); }
        append8(kk, tb2, vt2);
    }
    {   // tile3 consume; refill slot with tile7
        unsigned kk[8];
        conv8(kk, A3, B3, vt3);
        if (vt7) { A3 = *(const float4*)(rowp + tb7); B3 = *(const float4*)(rowp + tb7 + 4); }
        append8(kk, tb3, vt3);
    }
    {   unsigned kk[8]; conv8(kk, A4, B4, vt4); append8(kk, tb4, vt4); }  // tile4
    {   unsigned kk[8]; conv8(kk, A5, B5, vt5); append8(kk, tb5, vt5); }  // tile5
    {   unsigned kk[8]; conv8(kk, A2, B2, vt6); append8(kk, tb6, vt6); }  // tile6
    {   unsigned kk[8]; conv8(kk, A3, B3, vt7); append8(kk, tb7, vt7); }  // tile7

    // generic tail for slices > 8 tiles (fallback nsl only)
    for (int t = s0 + 8 * WT; t < s_end; t += WT) {
        int bs = t + lane * 8;
        bool v = bs < s_end;
        float4 aa = {}, bb = {};
        if (v) { aa = *(const float4*)(rowp + bs); bb = *(const float4*)(rowp + bs + 4); }
        unsigned kk[8];
        conv8(kk, aa, bb, v);
        append8(kk, bs, v);
    }

    asm volatile("s_waitcnt lgkmcnt(0)" ::: "memory");
    __builtin_amdgcn_sched_barrier(0);
    unsigned n = cnt;                            // wave-uniform

    if (n > CAPW) {
        // ===== wave-local cold exact redo (adversarial data only) =====
        // Stored CAPW survivors' 64th-largest vst <= slice 64th-largest, so
        // re-streaming with > vst (front already holds enough ==vst copies)
        // loses nothing. Per-tile rebuild bounds cnt <= CAPW; terminates
        // (rebuild drops cnt to 64; 64 + 512 <= CAPW).
        unsigned vst;
        cnt = wave_rebuild64_g<16>(mykey, myidx, CAPW, lane, &vst);
        for (int t = s0; t < s_end; t += WT) {
            int bs = t + lane * 8;
            bool v = bs < s_end;
            float4 aa = {}, bb = {};
            if (v) { aa = *(const float4*)(rowp + bs); bb = *(const float4*)(rowp + bs + 4); }
            unsigned kk[8];
            conv8(kk, aa, bb, v);
            for (;;) {
                unsigned long long m[8]; unsigned tot = 0u;
                #pragma unroll
                for (int j = 0; j < 8; ++j) {
                    m[j] = __ballot(v && (kk[j] > vst));
                    tot += (unsigned)__popcll(m[j]);
                }
                if (cnt + tot <= CAPW) {
                    unsigned c2 = cnt;
                    #pragma unroll
                    for (int j = 0; j < 8; ++j) {
                        if (v && (kk[j] > vst)) {
                            unsigned pos = c2 + (unsigned)__popcll(m[j] & ltm);
                            mykey[pos] = kk[j]; myidx[pos] = bs + j;
                        }
                        c2 += (unsigned)__popcll(m[j]);
                    }
                    cnt = c2;
                    break;
                }
                asm volatile("s_waitcnt lgkmcnt(0)" ::: "memory");
                __builtin_amdgcn_sched_barrier(0);
                cnt = wave_rebuild64_g<16>(mykey, myidx, cnt, lane, &vst);
            }
        }
        asm volatile("s_waitcnt lgkmcnt(0)" ::: "memory");
        __builtin_amdgcn_sched_barrier(0);
        n = cnt;
    }

    // ---- final exact top-64 of the n survivors (handles n < 64 too) ----
    unsigned vfin;
    unsigned c2 = wave_rebuild64(mykey, myidx, n, lane, &vfin);
    asm volatile("s_waitcnt lgkmcnt(0)" ::: "memory");
    __builtin_amdgcn_sched_barrier(0);

    uint2* outp = cand + ((size_t)row * (unsigned)nsl + (unsigned)sl) * TOPC;
    unsigned e = (unsigned)lane;                 // TOPC == 64 == wave size
    uint2 val = (e < c2) ? make_uint2(mykey[e], (unsigned)myidx[e])
                         : make_uint2(0u, 0u);   // pad key 0 ranks last
    outp[e] = val;
}

// ---- block-cooperative 4-bit radix select (r5-verified) — phase2 only ----
__device__ unsigned radix_select_compact4(uint2* s_buf, uint2* s_keep,
                                          unsigned (*s_hist)[16], unsigned* p_cnt2,
                                          unsigned n, int tid, int wid)
{
    unsigned prefix = 0u;
    int remaining = TOPC;
    for (int shift = 28; shift >= 0; shift -= 4) {
        if (tid < 64) ((unsigned*)s_hist)[tid] = 0u;
        __syncthreads();
        for (unsigned i = (unsigned)tid; i < n; i += BT) {
            unsigned k = s_buf[i].x;
            bool ing = (shift == 28) || ((k >> (shift + 4)) == (prefix >> (shift + 4)));
            if (ing) atomicAdd(&s_hist[wid][(k >> shift) & 15u], 1u);
        }
        __syncthreads();
        int cum = 0; int b = 0; unsigned hb = 0u;
        for (int bb = 15; bb >= 0; --bb) {
            unsigned h = s_hist[0][bb] + s_hist[1][bb] + s_hist[2][bb] + s_hist[3][bb];
            cum += (int)h;
            if (cum >= remaining) { b = bb; hb = h; break; }
        }
        remaining -= (cum - (int)hb);
        prefix |= ((unsigned)b) << shift;
        __syncthreads();
    }
    if (tid == 0) *p_cnt2 = 0u;
    __syncthreads();
    for (unsigned i = (unsigned)tid; i < n; i += BT) {
        uint2 c = s_buf[i];
        if (c.x > prefix) s_keep[atomicAdd(p_cnt2, 1u)] = c;
    }
    __syncthreads();
    for (unsigned i = (unsigned)tid; i < n; i += BT) {
        uint2 c = s_buf[i];
        if (c.x == prefix) {
            unsigned pos = atomicAdd(p_cnt2, 1u);
            if (pos < TOPC) s_keep[pos] = c;
        }
    }
    __syncthreads();
    return prefix;
}

// Phase 2: one block per row (r5-verified logic; nc up to 2048).
__global__ __launch_bounds__(BT) void phase2_sample(
    const uint2* __restrict__ cand,
    const float* __restrict__ temperature,
    const int*   __restrict__ top_k,
    const float* __restrict__ top_p,
    const float* __restrict__ noise_u,
    float* __restrict__ out,
    int B, int V, int M, int nc)
{
    __shared__ uint2    s_buf[NC_MAX];      // 16 KB
    __shared__ uint2    s_keep[TOPC];
    __shared__ unsigned s_hist[4][16];
    __shared__ unsigned s_cnt2;
    __shared__ float    sval[TOPC], se[TOPC], sq[TOPC];
    __shared__ int      sidx[TOPC];

    const int r   = blockIdx.x;
    const int tid = threadIdx.x;
    const int wid = tid >> 6;

    for (int i = tid; i < nc; i += BT)
        s_buf[i] = cand[(size_t)r * nc + i];
    __syncthreads();
    radix_select_compact4(s_buf, s_keep, s_hist, &s_cnt2, (unsigned)nc, tid, wid);

    // bitonic sort s_keep[0..63] by (key desc, idx asc)
    for (int kk = 2; kk <= TOPC; kk <<= 1) {
        for (int j = kk >> 1; j > 0; j >>= 1) {
            if (tid < TOPC / 2) {
                int i0 = ((tid & ~(j - 1)) << 1) | (tid & (j - 1));
                int i1 = i0 | j;
                bool up = ((i0 & kk) == 0);
                uint2 A = s_keep[i0], Bv = s_keep[i1];
                bool gt = (A.x < Bv.x) || (A.x == Bv.x && A.y > Bv.y);
                if (gt == up) { s_keep[i0] = Bv; s_keep[i1] = A; }
            }
            __syncthreads();
        }
    }

    float temp_orig = temperature[r];
    float temp = (temp_orig < 1e-5f) ? 1.0f : temp_orig;

    if (tid < TOPC) {
        unsigned k = s_keep[tid].x;
        int id = (int)s_keep[tid].y;
        sval[tid] = ord2f(k) / temp;        // IEEE f32 divide == reference
        sidx[tid] = id;
        float u = noise_u[(size_t)r * (size_t)V + id];
        sq[tid] = -logf(u);                 // Exp(1) noise
    }
    __syncthreads();
    if (tid < TOPC) se[tid] = expf(sval[tid] - sval[0]);
    __syncthreads();

    if (tid == 0) {
        int k = top_k[r];
        if (k < 1) k = 1; if (k > TOPC) k = TOPC;
        float p = top_p[r];

        // top-k: pivot value (k-th largest scaled); keep all >= pivot (prefix)
        float pivot = sval[k - 1];
        int m = k;
        while (m < TOPC && sval[m] >= pivot) ++m;

        float sum = 0.f;
        for (int i = 0; i < m; ++i) sum += se[i];

        // top-p: ascending sequential cumsum of probs, drop while S <= 1-p
        float thr1 = 1.0f - p;
        float S = 0.f;
        int f = 1;                           // top token always kept
        for (int i = m - 1; i >= 1; --i) {
            S += se[i] / sum;                // per-element divide like ref
            if (S > thr1) { f = i + 1; break; }
        }

        float sum2 = 0.f;
        for (int i = 0; i < f; ++i) sum2 += se[i];

        int greedy = sidx[0];
        float best = -1.f; int bidx = 0x7fffffff;
        for (int i = 0; i < f; ++i) {
            float ratio = (se[i] / sum2) / sq[i];
            if (ratio > best || (ratio == best && sidx[i] < bidx)) {
                best = ratio; bidx = sidx[i];
            }
        }
        int sampled = (temp_orig < 1e-5f) ? greedy : bidx;

        float lse = logf(sum2);
        out[r] = (float)sampled;
        float* oidx = out + B + (size_t)r * M;
        float* olp  = out + B + (size_t)B * M + (size_t)r * M;
        int produced = 0;
        for (int i = 0; i < f && produced < M; ++i, ++produced) {
            oidx[produced] = (float)sidx[i];
            olp[produced]  = (sval[i] - sval[0]) - lse;
        }
        // finite sentinel at smallest non-kept indices (harness -inf rule)
        int v = 0;
        while (produced < M) {
            bool used = false;
            for (int i = 0; i < f; ++i) if (sidx[i] == v) { used = true; break; }
            if (!used) { oidx[produced] = (float)v; olp[produced] = -3.0e38f; ++produced; }
            ++v;
        }
    }
}

extern "C" void kernel_launch(void* const* d_in, const int* in_sizes, int n_in,
                              void* d_out, int out_size, void* d_ws, size_t ws_size,
                              hipStream_t stream)
{
    const float* logits      = (const float*)d_in[0];
    const float* temperature = (const float*)d_in[1];
    const int*   top_k       = (const int*)d_in[2];
    const float* top_p       = (const float*)d_in[3];
    const float* noise_u     = (const float*)d_in[4];

    const int B = in_sizes[1];
    const int V = in_sizes[0] / B;
    const int M = (out_size / B - 1) / 2;   // out = B + B*M + B*M

    const size_t need32 = (size_t)B * NSL_HI * TOPC * sizeof(uint2);  // 2 MB
    const int nsl = (ws_size >= need32) ? NSL_HI : NSL_LO;

    uint2* cand = (uint2*)d_ws;             // B * nsl * TOPC * 8 bytes

    int slice_len = (((V + nsl - 1) / nsl) + 7) & ~7;   // multiple of 8

    dim3 g1(nsl / WPB, B);
    phase1_topk_slices<<<g1, BT, 0, stream>>>(logits, cand, V, slice_len, nsl);
    phase2_sample<<<B, BT, 0, stream>>>(cand, temperature, top_k, top_p, noise_u,
                                        (float*)d_out, B, V, M, nsl * TOPC);
}

// Round 9
// 174.431 us; speedup vs baseline: 1.0319x; 1.0319x over previous
//
#include <hip/hip_runtime.h>
#include <math.h>
#include <stdint.h>

#define BT     256            // threads per block
#define WPB    4              // waves per block
#define TOPC   64             // outputs per slice (== wave size)
#define CAPW   640            // per-wave LDS survivor capacity (>= 64+512 for redo)
#define SUB    256            // subtile elements (64 lanes x 4 floats = 1 KB)
#define RING   8              // ring slots per wave (8 KB)
#define WT     512            // redo-path tile (lane*8)
#define NSL_HI 24             // slices/row (768 blocks = 3/CU exactly)
#define NSL_LO 8              // fallback (small workspace)
#define NC_MAX 2048           // phase2 candidate max

// order-preserving float <-> uint mapping (monotone increasing)
__device__ __forceinline__ unsigned f2ord(float f) {
    unsigned u = __float_as_uint(f);
    return u ^ ((u & 0x80000000u) ? 0xFFFFFFFFu : 0x80000000u);
}
__device__ __forceinline__ float ord2f(unsigned k) {
    unsigned u = (k & 0x80000000u) ? (k ^ 0x80000000u) : (k ^ 0xFFFFFFFFu);
    return __uint_as_float(u);
}

// async 16B-per-lane global->LDS DMA. lds base must be wave-uniform; HW writes
// lane i's 16B at base + i*16. gsrc is the PER-LANE global address.
__device__ __forceinline__ void async_copy16(const float* gsrc, unsigned* lds) {
    __builtin_amdgcn_global_load_lds(
        (const __attribute__((address_space(1))) void*)gsrc,
        (__attribute__((address_space(3))) void*)lds, 16, 0, 0);
}
// counted vmcnt wait + scheduling fence (guide rule 18: pin with sched_barrier)
#define WAITV(N) do { asm volatile("s_waitcnt vmcnt(" #N ")" ::: "memory"); \
                      __builtin_amdgcn_sched_barrier(0); } while (0)

// ---- wave-local exact top-64 rebuild (r7-verified; width-templated) ----
// key/idx[0..n) (n <= G*64, wave-uniform) -> exact TOPC-th largest vstar via
// 32-round bitwise ballot search; compacts (> vstar, then == vstar) to front.
// Returns min(n, TOPC); *out_vst = vstar. All lanes must call.
template<int G>
__device__ unsigned wave_rebuild64_g(unsigned* key, int* idx, unsigned n,
                                     int lane, unsigned* out_vst)
{
    unsigned kr[G]; int ir[G];
    #pragma unroll
    for (int g = 0; g < G; ++g) {
        unsigned i = (unsigned)(g * 64 + lane);
        kr[g] = (i < n) ? key[i] : 0u;
        ir[g] = (i < n) ? idx[i] : 0;
    }
    unsigned p = 0u;
    for (int bit = 31; bit >= 0; --bit) {
        unsigned t = p | (1u << bit);
        int c = 0;
        #pragma unroll
        for (int g = 0; g < G; ++g)
            c += __popcll(__ballot(kr[g] >= t));   // pads 0 never >= t (t != 0)
        if (c >= TOPC) p = t;
    }
    const unsigned long long ltm = (1ull << lane) - 1ull;
    unsigned c = 0;
    #pragma unroll
    for (int g = 0; g < G; ++g) {                  // strictly greater (< TOPC)
        unsigned i = (unsigned)(g * 64 + lane);
        bool pa = (i < n) && (kr[g] > p);
        unsigned long long m = __ballot(pa);
        if (pa) { unsigned pos = c + (unsigned)__popcll(m & ltm); key[pos] = kr[g]; idx[pos] = ir[g]; }
        c += (unsigned)__popcll(m);
    }
    #pragma unroll
    for (int g = 0; g < G; ++g) {                  // equals fill to TOPC
        unsigned i = (unsigned)(g * 64 + lane);
        bool pa = (i < n) && (kr[g] == p);
        unsigned long long m = __ballot(pa);
        if (pa) {
            unsigned pos = c + (unsigned)__popcll(m & ltm);
            if (pos < TOPC) { key[pos] = kr[g]; idx[pos] = ir[g]; }
        }
        c += (unsigned)__popcll(m);
    }
    *out_vst = p;
    return (c < TOPC) ? c : TOPC;
}
__device__ __forceinline__ unsigned wave_rebuild64(unsigned* key, int* idx,
                                                   unsigned n, int lane,
                                                   unsigned* out_vst)
{
    if (n <= 256) return wave_rebuild64_g<4>(key, idx, n, lane, out_vst);
    if (n <= 512) return wave_rebuild64_g<8>(key, idx, n, lane, out_vst);
    return wave_rebuild64_g<12>(key, idx, n, lane, out_vst);   // covers CAPW=640
}

// Phase 1: one WAVE per slice; zero __syncthreads. Async global->LDS ring
// keeps 8-12 subtiles in flight per wave (DMA uses no VGPRs, so the compiler
// cannot serialize the loads). Ballot seed + ballot-prefix append + ballot
// rebuild are all wave-local (r7-verified).
__global__ __launch_bounds__(BT) void phase1_topk_slices(
    const float* __restrict__ logits, uint2* __restrict__ cand,
    int V, int slice_len, int nsl)
{
    __shared__ unsigned s_ring[WPB][RING * SUB];   // 32 KB
    __shared__ unsigned s_key[WPB][CAPW];          // 10 KB
    __shared__ int      s_idx[WPB][CAPW];          // 10 KB

    const int row  = blockIdx.y;
    const int tid  = threadIdx.x;
    const int wid  = tid >> 6;
    const int lane = tid & 63;
    const int sl   = blockIdx.x * WPB + wid;
    const int s0   = sl * slice_len;               // multiple of SUB
    int s_end = s0 + slice_len; if (s_end > V) s_end = V;
    const float* rowp = logits + (size_t)row * (size_t)V;
    unsigned* ring  = s_ring[wid];
    unsigned* mykey = s_key[wid];
    int*      myidx = s_idx[wid];
    const unsigned long long ltm = (1ull << lane) - 1ull;
    const int lane4 = lane * 4;

    uint2* outp = cand + ((size_t)row * (unsigned)nsl + (unsigned)sl) * TOPC;

    const int NSUB = (s_end > s0) ? ((s_end - s0 + SUB - 1) / SUB) : 0;
    if (NSUB <= 0) {                               // empty slice (never at bench V)
        outp[lane] = make_uint2(0u, 0u);
        return;
    }
    const int vclamp = V - 4;                      // safe per-lane src clamp

    auto issue = [&](int st) {                     // wave-uniform st
        int off = s0 + st * SUB + lane4;
        const float* g = rowp + ((off <= vclamp) ? off : vclamp);
        async_copy16(g, &ring[(st & (RING - 1)) * SUB]);
    };

    // ---- prologue: fill the ring ----
    const int ni0 = (NSUB < RING) ? NSUB : RING;
    for (int st = 0; st < ni0; ++st) issue(st);
    int issued = ni0;

    // ---- seed sample: subtiles 0..sseed-1 ----
    const int sseed = (NSUB < 4) ? NSUB : 4;
    if (NSUB >= RING) { WAITV(4); } else { WAITV(0); }

    unsigned kr[16];
    #pragma unroll
    for (int st = 0; st < 4; ++st) {
        if (st < sseed) {
            uint4 r = *(const uint4*)(&ring[st * SUB + lane4]);
            kr[st * 4 + 0] = f2ord(__uint_as_float(r.x));
            kr[st * 4 + 1] = f2ord(__uint_as_float(r.y));
            kr[st * 4 + 2] = f2ord(__uint_as_float(r.z));
            kr[st * 4 + 3] = f2ord(__uint_as_float(r.w));
        } else {
            kr[st * 4 + 0] = 0u; kr[st * 4 + 1] = 0u;
            kr[st * 4 + 2] = 0u; kr[st * 4 + 3] = 0u;
        }
    }

    // ---- seed threshold: 16-bit prefix ballot binary search (r5/r7-verified:
    //      count(sample >= thr) >= TOPC => every slice-top-64 passes >=) ----
    unsigned lo = 0u, hi = 0xFFFFu;
    while (lo < hi) {                              // exactly 16 iterations
        unsigned mid = (lo + hi + 1u) >> 1;
        unsigned t = mid << 16;
        int c16 = 0;
        #pragma unroll
        for (int j = 0; j < 16; ++j) c16 += __popcll(__ballot(kr[j] >= t));
        if (c16 >= TOPC) lo = mid; else hi = mid - 1u;
    }
    const unsigned thr = lo << 16;

    // ---- append: ballot-prefix positions, wave-uniform count (all lanes call)
    unsigned cnt = 0u;
    auto append4 = [&](const unsigned* k, int base) {
        #pragma unroll
        for (int j = 0; j < 4; ++j) {
            bool pa = (base + j < s_end) && (k[j] >= thr);
            unsigned long long m = __ballot(pa);
            if (pa) {
                unsigned pos = cnt + (unsigned)__popcll(m & ltm);
                if (pos < CAPW) { mykey[pos] = k[j]; myidx[pos] = base + j; }
            }
            cnt += (unsigned)__popcll(m);
        }
    };

    #pragma unroll
    for (int st = 0; st < 4; ++st)
        if (st < sseed) append4(&kr[st * 4], s0 + st * SUB + lane4);

    // ---- top up in-flight to i+8 before steady loop ----
    {
        const int tgt = (NSUB < sseed + RING) ? NSUB : (sseed + RING);
        for (; issued < tgt; ++issued) issue(issued);
    }

    // ---- steady: consume i, reissue i+8; 8 DMAs always in flight ----
    int i = sseed;
    for (; i + RING < NSUB; ++i) {
        WAITV(7);                                  // subtile i complete (in-order)
        uint4 r = *(const uint4*)(&ring[(i & (RING - 1)) * SUB + lane4]);
        unsigned kk[4];
        kk[0] = f2ord(__uint_as_float(r.x)); kk[1] = f2ord(__uint_as_float(r.y));
        kk[2] = f2ord(__uint_as_float(r.z)); kk[3] = f2ord(__uint_as_float(r.w));
        issue(i + RING); ++issued;                 // slot (i&7): already consumed
        append4(kk, s0 + i * SUB + lane4);
    }
    // ---- drain ----
    WAITV(0);
    for (; i < NSUB; ++i) {
        uint4 r = *(const uint4*)(&ring[(i & (RING - 1)) * SUB + lane4]);
        unsigned kk[4];
        kk[0] = f2ord(__uint_as_float(r.x)); kk[1] = f2ord(__uint_as_float(r.y));
        kk[2] = f2ord(__uint_as_float(r.z)); kk[3] = f2ord(__uint_as_float(r.w));
        append4(kk, s0 + i * SUB + lane4);
    }

    unsigned n = cnt;                              // wave-uniform true count

    if (n > CAPW) {
        // ===== wave-local cold exact redo (adversarial data only; r7-verified
        // structure). First CAPW stored passers' 64th >= threshold vst <= true
        // 64th; re-stream with > vst. Terminates: 64 + 512 <= CAPW. =====
        unsigned vst;
        cnt = wave_rebuild64_g<12>(mykey, myidx, CAPW, lane, &vst);
        for (int t = s0; t < s_end; t += WT) {
            int bs = t + lane * 8;
            bool v = bs < s_end;                   // V multiple of 8 (bench)
            float4 aa = {}, bb = {};
            if (v) { aa = *(const float4*)(rowp + bs); bb = *(const float4*)(rowp + bs + 4); }
            unsigned kk[8];
            if (v) {
                kk[0] = f2ord(aa.x); kk[1] = f2ord(aa.y); kk[2] = f2ord(aa.z); kk[3] = f2ord(aa.w);
                kk[4] = f2ord(bb.x); kk[5] = f2ord(bb.y); kk[6] = f2ord(bb.z); kk[7] = f2ord(bb.w);
            } else {
                #pragma unroll
                for (int j = 0; j < 8; ++j) kk[j] = 0u;
            }
            for (;;) {
                unsigned long long m[8]; unsigned tot = 0u;
                #pragma unroll
                for (int j = 0; j < 8; ++j) {
                    m[j] = __ballot(v && (kk[j] > vst));
                    tot += (unsigned)__popcll(m[j]);
                }
                if (cnt + tot <= CAPW) {
                    unsigned c2 = cnt;
                    #pragma unroll
                    for (int j = 0; j < 8; ++j) {
                        if (v && (kk[j] > vst)) {
                            unsigned pos = c2 + (unsigned)__popcll(m[j] & ltm);
                            mykey[pos] = kk[j]; myidx[pos] = bs + j;
                        }
                        c2 += (unsigned)__popcll(m[j]);
                    }
                    cnt = c2;
                    break;
                }
                cnt = wave_rebuild64_g<12>(mykey, myidx, cnt, lane, &vst);
            }
        }
        n = cnt;
    }

    // ---- final exact top-64 (handles n < 64 via pads) and coalesced write ----
    unsigned vfin;
    unsigned c2 = wave_rebuild64(mykey, myidx, n, lane, &vfin);
    uint2 val = ((unsigned)lane < c2)
              ? make_uint2(mykey[lane], (unsigned)myidx[lane])
              : make_uint2(0u, 0u);                // pad key 0 ranks last
    outp[lane] = val;
}

// ---- block-cooperative 4-bit radix select (r5-verified) — phase2 only ----
__device__ unsigned radix_select_compact4(uint2* s_buf, uint2* s_keep,
                                          unsigned (*s_hist)[16], unsigned* p_cnt2,
                                          unsigned n, int tid, int wid)
{
    unsigned prefix = 0u;
    int remaining = TOPC;
    for (int shift = 28; shift >= 0; shift -= 4) {
        if (tid < 64) ((unsigned*)s_hist)[tid] = 0u;
        __syncthreads();
        for (unsigned i = (unsigned)tid; i < n; i += BT) {
            unsigned k = s_buf[i].x;
            bool ing = (shift == 28) || ((k >> (shift + 4)) == (prefix >> (shift + 4)));
            if (ing) atomicAdd(&s_hist[wid][(k >> shift) & 15u], 1u);
        }
        __syncthreads();
        int cum = 0; int b = 0; unsigned hb = 0u;
        for (int bb = 15; bb >= 0; --bb) {
            unsigned h = s_hist[0][bb] + s_hist[1][bb] + s_hist[2][bb] + s_hist[3][bb];
            cum += (int)h;
            if (cum >= remaining) { b = bb; hb = h; break; }
        }
        remaining -= (cum - (int)hb);
        prefix |= ((unsigned)b) << shift;
        __syncthreads();
    }
    if (tid == 0) *p_cnt2 = 0u;
    __syncthreads();
    for (unsigned i = (unsigned)tid; i < n; i += BT) {
        uint2 c = s_buf[i];
        if (c.x > prefix) s_keep[atomicAdd(p_cnt2, 1u)] = c;
    }
    __syncthreads();
    for (unsigned i = (unsigned)tid; i < n; i += BT) {
        uint2 c = s_buf[i];
        if (c.x == prefix) {
            unsigned pos = atomicAdd(p_cnt2, 1u);
            if (pos < TOPC) s_keep[pos] = c;
        }
    }
    __syncthreads();
    return prefix;
}

// Phase 2: one block per row (r5-verified logic; nc up to 2048).
__global__ __launch_bounds__(BT) void phase2_sample(
    const uint2* __restrict__ cand,
    const float* __restrict__ temperature,
    const int*   __restrict__ top_k,
    const float* __restrict__ top_p,
    const float* __restrict__ noise_u,
    float* __restrict__ out,
    int B, int V, int M, int nc)
{
    __shared__ uint2    s_buf[NC_MAX];
    __shared__ uint2    s_keep[TOPC];
    __shared__ unsigned s_hist[4][16];
    __shared__ unsigned s_cnt2;
    __shared__ float    sval[TOPC], se[TOPC], sq[TOPC];
    __shared__ int      sidx[TOPC];

    const int r   = blockIdx.x;
    const int tid = threadIdx.x;
    const int wid = tid >> 6;

    for (int i = tid; i < nc; i += BT)
        s_buf[i] = cand[(size_t)r * nc + i];
    __syncthreads();
    radix_select_compact4(s_buf, s_keep, s_hist, &s_cnt2, (unsigned)nc, tid, wid);

    // bitonic sort s_keep[0..63] by (key desc, idx asc)
    for (int kk = 2; kk <= TOPC; kk <<= 1) {
        for (int j = kk >> 1; j > 0; j >>= 1) {
            if (tid < TOPC / 2) {
                int i0 = ((tid & ~(j - 1)) << 1) | (tid & (j - 1));
                int i1 = i0 | j;
                bool up = ((i0 & kk) == 0);
                uint2 A = s_keep[i0], Bv = s_keep[i1];
                bool gt = (A.x < Bv.x) || (A.x == Bv.x && A.y > Bv.y);
                if (gt == up) { s_keep[i0] = Bv; s_keep[i1] = A; }
            }
            __syncthreads();
        }
    }

    float temp_orig = temperature[r];
    float temp = (temp_orig < 1e-5f) ? 1.0f : temp_orig;

    if (tid < TOPC) {
        unsigned k = s_keep[tid].x;
        int id = (int)s_keep[tid].y;
        sval[tid] = ord2f(k) / temp;        // IEEE f32 divide == reference
        sidx[tid] = id;
        float u = noise_u[(size_t)r * (size_t)V + id];
        sq[tid] = -logf(u);                 // Exp(1) noise
    }
    __syncthreads();
    if (tid < TOPC) se[tid] = expf(sval[tid] - sval[0]);
    __syncthreads();

    if (tid == 0) {
        int k = top_k[r];
        if (k < 1) k = 1; if (k > TOPC) k = TOPC;
        float p = top_p[r];

        // top-k: pivot value (k-th largest scaled); keep all >= pivot (prefix)
        float pivot = sval[k - 1];
        int m = k;
        while (m < TOPC && sval[m] >= pivot) ++m;

        float sum = 0.f;
        for (int i = 0; i < m; ++i) sum += se[i];

        // top-p: ascending sequential cumsum of probs, drop while S <= 1-p
        float thr1 = 1.0f - p;
        float S = 0.f;
        int f = 1;                           // top token always kept
        for (int i = m - 1; i >= 1; --i) {
            S += se[i] / sum;                // per-element divide like ref
            if (S > thr1) { f = i + 1; break; }
        }

        float sum2 = 0.f;
        for (int i = 0; i < f; ++i) sum2 += se[i];

        int greedy = sidx[0];
        float best = -1.f; int bidx = 0x7fffffff;
        for (int i = 0; i < f; ++i) {
            float ratio = (se[i] / sum2) / sq[i];
            if (ratio > best || (ratio == best && sidx[i] < bidx)) {
                best = ratio; bidx = sidx[i];
            }
        }
        int sampled = (temp_orig < 1e-5f) ? greedy : bidx;

        float lse = logf(sum2);
        out[r] = (float)sampled;
        float* oidx = out + B + (size_t)r * M;
        float* olp  = out + B + (size_t)B * M + (size_t)r * M;
        int produced = 0;
        for (int i = 0; i < f && produced < M; ++i, ++produced) {
            oidx[produced] = (float)sidx[i];
            olp[produced]  = (sval[i] - sval[0]) - lse;
        }
        // finite sentinel at smallest non-kept indices (harness -inf rule)
        int v = 0;
        while (produced < M) {
            bool used = false;
            for (int i = 0; i < f; ++i) if (sidx[i] == v) { used = true; break; }
            if (!used) { oidx[produced] = (float)v; olp[produced] = -3.0e38f; ++produced; }
            ++v;
        }
    }
}

extern "C" void kernel_launch(void* const* d_in, const int* in_sizes, int n_in,
                              void* d_out, int out_size, void* d_ws, size_t ws_size,
                              hipStream_t stream)
{
    const float* logits      = (const float*)d_in[0];
    const float* temperature = (const float*)d_in[1];
    const int*   top_k       = (const int*)d_in[2];
    const float* top_p       = (const float*)d_in[3];
    const float* noise_u     = (const float*)d_in[4];

    const int B = in_sizes[1];
    const int V = in_sizes[0] / B;
    const int M = (out_size / B - 1) / 2;   // out = B + B*M + B*M

    const size_t needHI = (size_t)B * NSL_HI * TOPC * sizeof(uint2);  // 768 KB
    const int nsl = (ws_size >= needHI) ? NSL_HI : NSL_LO;

    uint2* cand = (uint2*)d_ws;             // B * nsl * TOPC * 8 bytes

    // slice_len: multiple of SUB(256) covering V/nsl
    int slice_len = (((V + nsl - 1) / nsl) + SUB - 1) & ~(SUB - 1);

    dim3 g1(nsl / WPB, B);
    phase1_topk_slices<<<g1, BT, 0, stream>>>(logits, cand, V, slice_len, nsl);
    phase2_sample<<<B, BT, 0, stream>>>(cand, temperature, top_k, top_p, noise_u,
                                        (float*)d_out, B, V, M, nsl * TOPC);
}